// Round 1
// baseline (545.147 us; speedup 1.0000x reference)
//
#include <hip/hip_runtime.h>
#include <hip/hip_cooperative_groups.h>
#include <math.h>

namespace cg = cooperative_groups;

// GCN link predictor, sparse-cone evaluation (round 3).
// Round-2 analysis: intrinsic work ~= 10-15 us (3x 6.4MB dst scans + ~600-node
// cone math) but dur_us = 128.8 -> launch/serialization bound across 8
// dependent dispatches. This round: single cooperative kernel, 6 grid.sync()s.
// The agg1e atomic pass + its 1MB zero are folded into the h1 phase (each F1
// wave rescans the ~550-entry e2 list with uniform scalar loads).
//
// Phases (one launch):
//  P0  zero ctrl/deg/bitmaps                        (replaces hipMemsetAsync)
//  P1  scan dst: collect e1 = edges with dst in {p0,p1}
//  P2  build F1 = {p0,p1} U src(e1); bmF1 + need bits + pos1
//  P3  scan dst: collect e2 = edges with dst in F1; need-bit src(e2)
//  P4  scan dst: deg[d]++ only if need-bit[d]       (~10k atomics)
//  P5  per-F1-row: agg over e2 (rescan) + self term, then @W1+b1, relu
//  P6  block 0: layer-2 agg over e1 + @W2+b2, relu, fc, sigmoid

#define CH 64
#define E1CAP 4096
#define F1CAP (E1CAP + 2)
#define E2CAP 131072
#define GRID 512
#define BLK 256

struct Params {
    const float* x;
    const int* src;
    const int* dst;
    const int* np_;
    const float* W1; const float* b1;
    const float* W2; const float* b2;
    const float* fcW; const float* fcb;
    int* ctrl; int* deg;
    unsigned* bmF1; unsigned* bmNd;
    int* pos1; int* e1s; int* e1d; int* F1;
    int* e2s; int* e2d; float* h1;
    float* out;
    int E; int N; int bmN;
};

__device__ __forceinline__ float dinv_of(int degv) {
    return rsqrtf((float)(degv + 1));
}

__device__ __forceinline__ void phase_zero(int gid, int gsz, int N, int bmN,
                                           int* ctrl, int* deg,
                                           unsigned* bmF1, unsigned* bmNd) {
    if (gid < 16) ctrl[gid] = 0;
    for (int i = gid; i < N; i += gsz) deg[i] = 0;
    for (int i = gid; i < bmN; i += gsz) { bmF1[i] = 0u; bmNd[i] = 0u; }
}

__device__ __forceinline__ void phase_e1(int gid, int gsz, const int* __restrict__ src,
                                         const int* __restrict__ dst, int E,
                                         int p0, int p1,
                                         int* ctrl, int* e1s, int* e1d) {
    const int nvec = E >> 2;
    const int4* dst4 = (const int4*)dst;
    for (int i = gid; i < nvec; i += gsz) {
        int4 d4 = dst4[i];
        int ds[4] = {d4.x, d4.y, d4.z, d4.w};
#pragma unroll
        for (int k = 0; k < 4; k++) {
            int d = ds[k];
            if (d == p0 || d == p1) {
                int idx = atomicAdd(&ctrl[0], 1);
                if (idx < E1CAP) { e1s[idx] = src[i * 4 + k]; e1d[idx] = d; }
            }
        }
    }
    for (int e = (nvec << 2) + gid; e < E; e += gsz) {
        int d = dst[e];
        if (d == p0 || d == p1) {
            int idx = atomicAdd(&ctrl[0], 1);
            if (idx < E1CAP) { e1s[idx] = src[e]; e1d[idx] = d; }
        }
    }
}

__device__ __forceinline__ void phase_f1(int gid, int gsz, const int* np_,
                                         const int* e1s, int* ctrl,
                                         unsigned* bmF1, unsigned* bmNd,
                                         int* pos1, int* F1) {
    int cnt1 = min(ctrl[0], E1CAP);
    int total = cnt1 + 2;
    for (int i = gid; i < total; i += gsz) {
        int u = (i < cnt1) ? e1s[i] : np_[i - cnt1];
        unsigned bit = 1u << (u & 31);
        unsigned old = atomicOr(&bmF1[u >> 5], bit);
        if (!(old & bit)) {
            atomicOr(&bmNd[u >> 5], bit);
            int idx = atomicAdd(&ctrl[2], 1);
            F1[idx] = u;
            pos1[u] = idx;
        }
    }
}

__device__ __forceinline__ void phase_e2(int gid, int gsz, const int* __restrict__ src,
                                         const int* __restrict__ dst, int E,
                                         const unsigned* __restrict__ bmF1,
                                         unsigned* bmNd, int* ctrl,
                                         int* e2s, int* e2d) {
    const int nvec = E >> 2;
    const int4* dst4 = (const int4*)dst;
    for (int i = gid; i < nvec; i += gsz) {
        int4 d4 = dst4[i];
        int ds[4] = {d4.x, d4.y, d4.z, d4.w};
#pragma unroll
        for (int k = 0; k < 4; k++) {
            int d = ds[k];
            if ((bmF1[d >> 5] >> (d & 31)) & 1u) {
                int s = src[i * 4 + k];
                atomicOr(&bmNd[s >> 5], 1u << (s & 31));
                int idx = atomicAdd(&ctrl[1], 1);
                if (idx < E2CAP) { e2s[idx] = s; e2d[idx] = d; }
            }
        }
    }
    for (int e = (nvec << 2) + gid; e < E; e += gsz) {
        int d = dst[e];
        if ((bmF1[d >> 5] >> (d & 31)) & 1u) {
            int s = src[e];
            atomicOr(&bmNd[s >> 5], 1u << (s & 31));
            int idx = atomicAdd(&ctrl[1], 1);
            if (idx < E2CAP) { e2s[idx] = s; e2d[idx] = d; }
        }
    }
}

__device__ __forceinline__ void phase_deg(int gid, int gsz,
                                          const int* __restrict__ dst, int E,
                                          const unsigned* __restrict__ bmNd,
                                          int* deg) {
    const int nvec = E >> 2;
    const int4* dst4 = (const int4*)dst;
    for (int i = gid; i < nvec; i += gsz) {
        int4 d4 = dst4[i];
        int ds[4] = {d4.x, d4.y, d4.z, d4.w};
#pragma unroll
        for (int k = 0; k < 4; k++) {
            int d = ds[k];
            if ((bmNd[d >> 5] >> (d & 31)) & 1u) atomicAdd(&deg[d], 1);
        }
    }
    for (int e = (nvec << 2) + gid; e < E; e += gsz) {
        int d = dst[e];
        if ((bmNd[d >> 5] >> (d & 31)) & 1u) atomicAdd(&deg[d], 1);
    }
}

// One row per wave, 4 waves/block. Each wave rescans the (tiny) e2 list with
// wave-uniform scalar loads; x-row reads are 256B coalesced per matching edge.
__device__ __forceinline__ void phase_h1(int blockId, int nBlocks, int tid,
                                         const float* __restrict__ x,
                                         const float* __restrict__ W1,
                                         const float* __restrict__ b1,
                                         const int* __restrict__ deg,
                                         const int* __restrict__ F1,
                                         const int* __restrict__ ctrl,
                                         const int* __restrict__ e2s,
                                         const int* __restrict__ e2d,
                                         float* __restrict__ h1,
                                         float (*a)[CH]) {
    int nf1 = min(ctrl[2], F1CAP);
    int cnt2 = min(ctrl[1], E2CAP);
    int w = tid >> 6, j = tid & 63;
    for (int base = blockId * 4; base < nf1; base += nBlocks * 4) {
        int i = base + w;
        if (i < nf1) {
            int u = F1[i];
            float du = dinv_of(deg[u]);
            float acc = du * du * x[(size_t)u * CH + j];
            for (int e = 0; e < cnt2; e++) {
                if (e2d[e] == u) {
                    int s = e2s[e];
                    acc += dinv_of(deg[s]) * du * x[(size_t)s * CH + j];
                }
            }
            a[w][j] = acc;       // same-wave LDS RAW: no barrier needed
            float sum = b1[j];
#pragma unroll
            for (int k = 0; k < CH; k++) sum += a[w][k] * W1[k * CH + j];
            h1[i * CH + j] = fmaxf(sum, 0.f);
        }
    }
}

__device__ __forceinline__ void phase_tail(int tid,
                                           const float* __restrict__ h1,
                                           const int* __restrict__ deg,
                                           const int* __restrict__ pos1,
                                           const int* __restrict__ np_,
                                           const int* __restrict__ ctrl,
                                           const int* __restrict__ e1s,
                                           const int* __restrict__ e1d,
                                           const float* __restrict__ W2,
                                           const float* __restrict__ b2,
                                           const float* __restrict__ fcW,
                                           const float* __restrict__ fcb,
                                           float* __restrict__ out,
                                           float (*a2)[CH], float* partial) {
    int t = tid >> 6, j = tid & 63;
    if (tid < 128) {
        int pp = np_[t];
        float dp = dinv_of(deg[pp]);
        float acc = dp * dp * h1[pos1[pp] * CH + j];
        int cnt1 = min(ctrl[0], E1CAP);
        for (int e = 0; e < cnt1; e++) {
            if (e1d[e] == pp) {
                int s = e1s[e];
                acc += dinv_of(deg[s]) * dp * h1[pos1[s] * CH + j];
            }
        }
        a2[t][j] = acc;
    }
    __syncthreads();
    if (tid < 128) {
        float sum = b2[j];
#pragma unroll
        for (int k = 0; k < CH; k++) sum += a2[t][k] * W2[k * CH + j];
        float v = fmaxf(sum, 0.f);
        float pr = v * fcW[t * CH + j];
        for (int off = 32; off > 0; off >>= 1) pr += __shfl_down(pr, off);
        if (j == 0) partial[t] = pr;
    }
    __syncthreads();
    if (tid == 0) {
        float z = partial[0] + partial[1] + fcb[0];
        out[0] = 1.f / (1.f + expf(-z));
    }
}

__global__ __launch_bounds__(BLK, 2) void k_fused(Params p) {
    cg::grid_group grid = cg::this_grid();
    __shared__ float a[4][CH];
    __shared__ float a2[2][CH];
    __shared__ float partial[2];
    const int gid = blockIdx.x * BLK + threadIdx.x;
    const int gsz = gridDim.x * BLK;

    phase_zero(gid, gsz, p.N, p.bmN, p.ctrl, p.deg, p.bmF1, p.bmNd);
    grid.sync();
    phase_e1(gid, gsz, p.src, p.dst, p.E, p.np_[0], p.np_[1], p.ctrl, p.e1s, p.e1d);
    grid.sync();
    phase_f1(gid, gsz, p.np_, p.e1s, p.ctrl, p.bmF1, p.bmNd, p.pos1, p.F1);
    grid.sync();
    phase_e2(gid, gsz, p.src, p.dst, p.E, p.bmF1, p.bmNd, p.ctrl, p.e2s, p.e2d);
    grid.sync();
    phase_deg(gid, gsz, p.dst, p.E, p.bmNd, p.deg);
    grid.sync();
    phase_h1(blockIdx.x, gridDim.x, threadIdx.x, p.x, p.W1, p.b1, p.deg, p.F1,
             p.ctrl, p.e2s, p.e2d, p.h1, a);
    grid.sync();
    if (blockIdx.x == 0)
        phase_tail(threadIdx.x, p.h1, p.deg, p.pos1, p.np_, p.ctrl, p.e1s, p.e1d,
                   p.W2, p.b2, p.fcW, p.fcb, p.out, a2, partial);
}

// ---- fallback path (non-cooperative), same phase bodies ----
__global__ void kf_zero(Params p) {
    int gid = blockIdx.x * blockDim.x + threadIdx.x;
    int gsz = gridDim.x * blockDim.x;
    phase_zero(gid, gsz, p.N, p.bmN, p.ctrl, p.deg, p.bmF1, p.bmNd);
}
__global__ void kf_e1(Params p) {
    int gid = blockIdx.x * blockDim.x + threadIdx.x;
    int gsz = gridDim.x * blockDim.x;
    phase_e1(gid, gsz, p.src, p.dst, p.E, p.np_[0], p.np_[1], p.ctrl, p.e1s, p.e1d);
}
__global__ void kf_f1(Params p) {
    int gid = blockIdx.x * blockDim.x + threadIdx.x;
    int gsz = gridDim.x * blockDim.x;
    phase_f1(gid, gsz, p.np_, p.e1s, p.ctrl, p.bmF1, p.bmNd, p.pos1, p.F1);
}
__global__ void kf_e2(Params p) {
    int gid = blockIdx.x * blockDim.x + threadIdx.x;
    int gsz = gridDim.x * blockDim.x;
    phase_e2(gid, gsz, p.src, p.dst, p.E, p.bmF1, p.bmNd, p.ctrl, p.e2s, p.e2d);
}
__global__ void kf_deg(Params p) {
    int gid = blockIdx.x * blockDim.x + threadIdx.x;
    int gsz = gridDim.x * blockDim.x;
    phase_deg(gid, gsz, p.dst, p.E, p.bmNd, p.deg);
}
__global__ void kf_h1(Params p) {
    __shared__ float a[4][CH];
    phase_h1(blockIdx.x, gridDim.x, threadIdx.x, p.x, p.W1, p.b1, p.deg, p.F1,
             p.ctrl, p.e2s, p.e2d, p.h1, a);
}
__global__ void kf_tail(Params p) {
    __shared__ float a2[2][CH];
    __shared__ float partial[2];
    phase_tail(threadIdx.x, p.h1, p.deg, p.pos1, p.np_, p.ctrl, p.e1s, p.e1d,
               p.W2, p.b2, p.fcW, p.fcb, p.out, a2, partial);
}

extern "C" void kernel_launch(void* const* d_in, const int* in_sizes, int n_in,
                              void* d_out, int out_size, void* d_ws, size_t ws_size,
                              hipStream_t stream) {
    const float* x   = (const float*)d_in[0];
    const int*   ei  = (const int*)d_in[1];
    const int*   np_ = (const int*)d_in[2];

    const int N = in_sizes[0] / CH;
    const int E = in_sizes[1] / 2;
    const int bmN = (N + 31) / 32;

    char* w = (char*)d_ws;
    size_t off = 0;
    auto alloc = [&](size_t bytes) {
        size_t o = off;
        off = (off + bytes + 255) & ~((size_t)255);
        return o;
    };
    size_t o_ctrl = alloc(64);
    size_t o_deg  = alloc((size_t)N * 4);
    size_t o_bmF1 = alloc((size_t)bmN * 4);
    size_t o_bmNd = alloc((size_t)bmN * 4);
    size_t o_pos  = alloc((size_t)N * 4);
    size_t o_e1s  = alloc((size_t)E1CAP * 4);
    size_t o_e1d  = alloc((size_t)E1CAP * 4);
    size_t o_F1   = alloc((size_t)F1CAP * 4);
    size_t o_e2s  = alloc((size_t)E2CAP * 4);
    size_t o_e2d  = alloc((size_t)E2CAP * 4);
    size_t o_h1   = alloc((size_t)F1CAP * CH * 4);
    (void)ws_size;

    Params p;
    p.x    = x;
    p.src  = ei;
    p.dst  = ei + E;
    p.np_  = np_;
    p.W1   = (const float*)d_in[3];
    p.b1   = (const float*)d_in[4];
    p.W2   = (const float*)d_in[5];
    p.b2   = (const float*)d_in[6];
    p.fcW  = (const float*)d_in[7];
    p.fcb  = (const float*)d_in[8];
    p.ctrl = (int*)(w + o_ctrl);
    p.deg  = (int*)(w + o_deg);
    p.bmF1 = (unsigned*)(w + o_bmF1);
    p.bmNd = (unsigned*)(w + o_bmNd);
    p.pos1 = (int*)(w + o_pos);
    p.e1s  = (int*)(w + o_e1s);
    p.e1d  = (int*)(w + o_e1d);
    p.F1   = (int*)(w + o_F1);
    p.e2s  = (int*)(w + o_e2s);
    p.e2d  = (int*)(w + o_e2d);
    p.h1   = (float*)(w + o_h1);
    p.out  = (float*)d_out;
    p.E = E; p.N = N; p.bmN = bmN;

    void* kargs[] = { &p };
    hipError_t err = hipLaunchCooperativeKernel((const void*)k_fused,
                                                dim3(GRID), dim3(BLK),
                                                kargs, 0, stream);
    if (err != hipSuccess) {
        // Fallback: multi-kernel path (round-2 structure, phase bodies shared)
        int scanBlocks = (E / 4 + 255) / 256;
        if (scanBlocks < 1) scanBlocks = 1;
        if (scanBlocks > 8192) scanBlocks = 8192;
        kf_zero<<<512, 256, 0, stream>>>(p);
        kf_e1<<<scanBlocks, 256, 0, stream>>>(p);
        kf_f1<<<(F1CAP + 255) / 256, 256, 0, stream>>>(p);
        kf_e2<<<scanBlocks, 256, 0, stream>>>(p);
        kf_deg<<<scanBlocks, 256, 0, stream>>>(p);
        kf_h1<<<160, 256, 0, stream>>>(p);
        kf_tail<<<1, 256, 0, stream>>>(p);
    }
}

// Round 3
// 261.633 us; speedup vs baseline: 2.0836x; 2.0836x over previous
//
#include <hip/hip_runtime.h>
#include <math.h>

// GCN link predictor, sparse-cone evaluation (round 5 = round 4 + compile fix).
// Round-3 post-mortem: cg::grid.sync() costs ~73 us each at 512 blocks
// (454 us kernel, 0.13% HBM, 0.5% VALU => pure barrier spin). This round:
//  - hand-rolled agent-scope grid barrier (~us, not ~73 us)
//    (fix: fence builtin is __builtin_amdgcn_fence, not __hip_atomic_fence)
//  - 6 syncs -> 4: F1-registration folded into the e1 scan; zero-phase hoisted
//    into the (required anyway) hipMemsetAsync that initializes barrier state
//  - 128 blocks x 512 threads (barrier arrival cost ~ block count; the three
//    6.4MB dst scans are L2/L3-resident and don't need full-chip parallelism)
//
// Single cooperative launch, phases:
//  P1  scan dst: e1 = edges with dst in {p0,p1}; register src(e1)+{p0,p1}
//      into F1 (bitmap dedup, pos1, need bits)                      -- bar --
//  P2  scan dst: e2 = edges with dst in F1; need-bit src(e2)        -- bar --
//  P3  scan dst: deg[d]++ if need-bit[d]   (~10k atomics)           -- bar --
//  P4  per-F1-row (1 row/wave): agg over e2 rescan + self, @W1+b1, relu -- bar
//  P5  block 0: layer-2 agg over e1 + @W2+b2, relu, fc, sigmoid

#define CH 64
#define E1CAP 4096
#define F1CAP (E1CAP + 2)
#define E2CAP 131072
#define GRID 128
#define BLK 512
#define NWAVE (BLK / 64)

struct Params {
    const float* x;
    const int* src; const int* dst; const int* np_;
    const float* W1; const float* b1;
    const float* W2; const float* b2;
    const float* fcW; const float* fcb;
    int* bar;          // [0]=arrive cnt, [32]=generation (separate cachelines)
    int* ctrl;         // [0]=cnt_e1 [1]=cnt_e2 [2]=nf1
    int* deg;
    unsigned* bmF1; unsigned* bmNd;
    int* pos1; int* e1s; int* e1d; int* F1;
    int* e2s; int* e2d; float* h1;
    float* out;
    int E; int N; int bmN; int nblocks;
};

__device__ __forceinline__ float dinv_of(int degv) {
    return rsqrtf((float)(degv + 1));
}

// Sense-counting grid barrier, agent (device) scope.
// Arrival: ACQ_REL fetch_add publishes this block's phase writes and (for the
// last arriver) acquires everyone else's. Publish: RELEASE store of gen+1.
// Waiters: relaxed spin, then acquire fence => see all pre-barrier writes.
__device__ __forceinline__ void gbar(int* bar, int nb) {
    __syncthreads();
    if (threadIdx.x == 0) {
        int g = __hip_atomic_load(&bar[32], __ATOMIC_RELAXED, __HIP_MEMORY_SCOPE_AGENT);
        int old = __hip_atomic_fetch_add(&bar[0], 1, __ATOMIC_ACQ_REL, __HIP_MEMORY_SCOPE_AGENT);
        if (old == nb - 1) {
            __hip_atomic_store(&bar[0], 0, __ATOMIC_RELAXED, __HIP_MEMORY_SCOPE_AGENT);
            __hip_atomic_store(&bar[32], g + 1, __ATOMIC_RELEASE, __HIP_MEMORY_SCOPE_AGENT);
        } else {
            while (__hip_atomic_load(&bar[32], __ATOMIC_RELAXED, __HIP_MEMORY_SCOPE_AGENT) == g)
                __builtin_amdgcn_s_sleep(1);
        }
        __builtin_amdgcn_fence(__ATOMIC_ACQUIRE, "agent");
    }
    __syncthreads();
}

__device__ __forceinline__ void reg_node(int u, unsigned* bmF1, unsigned* bmNd,
                                         int* ctrl, int* F1, int* pos1) {
    unsigned bit = 1u << (u & 31);
    unsigned old = atomicOr(&bmF1[u >> 5], bit);
    if (!(old & bit)) {
        atomicOr(&bmNd[u >> 5], bit);
        int i = atomicAdd(&ctrl[2], 1);
        F1[i] = u;
        pos1[u] = i;
    }
}

// P1: e1 collection + F1 registration fused (registration is per-match work).
__device__ __forceinline__ void phase_e1f1(int gid, int gsz,
                                           const int* __restrict__ src,
                                           const int* __restrict__ dst, int E,
                                           int p0, int p1, int* ctrl,
                                           int* e1s, int* e1d,
                                           unsigned* bmF1, unsigned* bmNd,
                                           int* F1, int* pos1) {
    if (gid == 0) {
        reg_node(p0, bmF1, bmNd, ctrl, F1, pos1);
        if (p1 != p0) reg_node(p1, bmF1, bmNd, ctrl, F1, pos1);
    }
    const int nvec = E >> 2;
    const int4* dst4 = (const int4*)dst;
    for (int i = gid; i < nvec; i += gsz) {
        int4 d4 = dst4[i];
        int ds[4] = {d4.x, d4.y, d4.z, d4.w};
#pragma unroll
        for (int k = 0; k < 4; k++) {
            int d = ds[k];
            if (d == p0 || d == p1) {
                int s = src[i * 4 + k];
                int idx = atomicAdd(&ctrl[0], 1);
                if (idx < E1CAP) { e1s[idx] = s; e1d[idx] = d; }
                reg_node(s, bmF1, bmNd, ctrl, F1, pos1);
            }
        }
    }
    for (int e = (nvec << 2) + gid; e < E; e += gsz) {
        int d = dst[e];
        if (d == p0 || d == p1) {
            int s = src[e];
            int idx = atomicAdd(&ctrl[0], 1);
            if (idx < E1CAP) { e1s[idx] = s; e1d[idx] = d; }
            reg_node(s, bmF1, bmNd, ctrl, F1, pos1);
        }
    }
}

__device__ __forceinline__ void phase_e2(int gid, int gsz,
                                         const int* __restrict__ src,
                                         const int* __restrict__ dst, int E,
                                         const unsigned* __restrict__ bmF1,
                                         unsigned* bmNd, int* ctrl,
                                         int* e2s, int* e2d) {
    const int nvec = E >> 2;
    const int4* dst4 = (const int4*)dst;
    for (int i = gid; i < nvec; i += gsz) {
        int4 d4 = dst4[i];
        int ds[4] = {d4.x, d4.y, d4.z, d4.w};
#pragma unroll
        for (int k = 0; k < 4; k++) {
            int d = ds[k];
            if ((bmF1[d >> 5] >> (d & 31)) & 1u) {
                int s = src[i * 4 + k];
                atomicOr(&bmNd[s >> 5], 1u << (s & 31));
                int idx = atomicAdd(&ctrl[1], 1);
                if (idx < E2CAP) { e2s[idx] = s; e2d[idx] = d; }
            }
        }
    }
    for (int e = (nvec << 2) + gid; e < E; e += gsz) {
        int d = dst[e];
        if ((bmF1[d >> 5] >> (d & 31)) & 1u) {
            int s = src[e];
            atomicOr(&bmNd[s >> 5], 1u << (s & 31));
            int idx = atomicAdd(&ctrl[1], 1);
            if (idx < E2CAP) { e2s[idx] = s; e2d[idx] = d; }
        }
    }
}

__device__ __forceinline__ void phase_deg(int gid, int gsz,
                                          const int* __restrict__ dst, int E,
                                          const unsigned* __restrict__ bmNd,
                                          int* deg) {
    const int nvec = E >> 2;
    const int4* dst4 = (const int4*)dst;
    for (int i = gid; i < nvec; i += gsz) {
        int4 d4 = dst4[i];
        int ds[4] = {d4.x, d4.y, d4.z, d4.w};
#pragma unroll
        for (int k = 0; k < 4; k++) {
            int d = ds[k];
            if ((bmNd[d >> 5] >> (d & 31)) & 1u) atomicAdd(&deg[d], 1);
        }
    }
    for (int e = (nvec << 2) + gid; e < E; e += gsz) {
        int d = dst[e];
        if ((bmNd[d >> 5] >> (d & 31)) & 1u) atomicAdd(&deg[d], 1);
    }
}

// One F1 row per wave; wave rescans the tiny e2 list with wave-uniform scalar
// loads, x-row reads are 256B coalesced per matching edge.
__device__ __forceinline__ void phase_h1(int blockId, int nBlocks, int tid,
                                         const float* __restrict__ x,
                                         const float* __restrict__ W1,
                                         const float* __restrict__ b1,
                                         const int* __restrict__ deg,
                                         const int* __restrict__ F1,
                                         const int* __restrict__ ctrl,
                                         const int* __restrict__ e2s,
                                         const int* __restrict__ e2d,
                                         float* __restrict__ h1,
                                         float (*a)[CH]) {
    int nf1 = min(ctrl[2], F1CAP);
    int cnt2 = min(ctrl[1], E2CAP);
    int w = tid >> 6, j = tid & 63;
    for (int base = blockId * NWAVE; base < nf1; base += nBlocks * NWAVE) {
        int i = base + w;
        if (i < nf1) {
            int u = F1[i];
            float du = dinv_of(deg[u]);
            float acc = du * du * x[(size_t)u * CH + j];
            for (int e = 0; e < cnt2; e++) {
                if (e2d[e] == u) {
                    int s = e2s[e];
                    acc += dinv_of(deg[s]) * du * x[(size_t)s * CH + j];
                }
            }
            a[w][j] = acc;       // same-wave LDS RAW: no barrier needed
            float sum = b1[j];
#pragma unroll
            for (int k = 0; k < CH; k++) sum += a[w][k] * W1[k * CH + j];
            h1[i * CH + j] = fmaxf(sum, 0.f);
        }
    }
}

__device__ __forceinline__ void phase_tail(int tid,
                                           const float* __restrict__ h1,
                                           const int* __restrict__ deg,
                                           const int* __restrict__ pos1,
                                           const int* __restrict__ np_,
                                           const int* __restrict__ ctrl,
                                           const int* __restrict__ e1s,
                                           const int* __restrict__ e1d,
                                           const float* __restrict__ W2,
                                           const float* __restrict__ b2,
                                           const float* __restrict__ fcW,
                                           const float* __restrict__ fcb,
                                           float* __restrict__ out,
                                           float (*a2)[CH], float* partial) {
    int t = tid >> 6, j = tid & 63;
    if (tid < 128) {
        int pp = np_[t];
        float dp = dinv_of(deg[pp]);
        float acc = dp * dp * h1[pos1[pp] * CH + j];
        int cnt1 = min(ctrl[0], E1CAP);
        for (int e = 0; e < cnt1; e++) {
            if (e1d[e] == pp) {
                int s = e1s[e];
                acc += dinv_of(deg[s]) * dp * h1[pos1[s] * CH + j];
            }
        }
        a2[t][j] = acc;
    }
    __syncthreads();
    if (tid < 128) {
        float sum = b2[j];
#pragma unroll
        for (int k = 0; k < CH; k++) sum += a2[t][k] * W2[k * CH + j];
        float v = fmaxf(sum, 0.f);
        float pr = v * fcW[t * CH + j];
        for (int off = 32; off > 0; off >>= 1) pr += __shfl_down(pr, off);
        if (j == 0) partial[t] = pr;
    }
    __syncthreads();
    if (tid == 0) {
        float z = partial[0] + partial[1] + fcb[0];
        out[0] = 1.f / (1.f + expf(-z));
    }
}

__global__ __launch_bounds__(BLK, 1) void k_fused(Params p) {
    __shared__ float a[NWAVE][CH];
    __shared__ float a2[2][CH];
    __shared__ float partial[2];
    const int gid = blockIdx.x * BLK + threadIdx.x;
    const int gsz = gridDim.x * BLK;

    phase_e1f1(gid, gsz, p.src, p.dst, p.E, p.np_[0], p.np_[1], p.ctrl,
               p.e1s, p.e1d, p.bmF1, p.bmNd, p.F1, p.pos1);
    gbar(p.bar, p.nblocks);
    phase_e2(gid, gsz, p.src, p.dst, p.E, p.bmF1, p.bmNd, p.ctrl, p.e2s, p.e2d);
    gbar(p.bar, p.nblocks);
    phase_deg(gid, gsz, p.dst, p.E, p.bmNd, p.deg);
    gbar(p.bar, p.nblocks);
    phase_h1(blockIdx.x, gridDim.x, threadIdx.x, p.x, p.W1, p.b1, p.deg, p.F1,
             p.ctrl, p.e2s, p.e2d, p.h1, a);
    gbar(p.bar, p.nblocks);
    if (blockIdx.x == 0)
        phase_tail(threadIdx.x, p.h1, p.deg, p.pos1, p.np_, p.ctrl, p.e1s, p.e1d,
                   p.W2, p.b2, p.fcW, p.fcb, p.out, a2, partial);
}

// ---- fallback path (non-cooperative multi-kernel), same phase bodies ----
__global__ void kf_e1f1(Params p) {
    int gid = blockIdx.x * blockDim.x + threadIdx.x;
    int gsz = gridDim.x * blockDim.x;
    phase_e1f1(gid, gsz, p.src, p.dst, p.E, p.np_[0], p.np_[1], p.ctrl,
               p.e1s, p.e1d, p.bmF1, p.bmNd, p.F1, p.pos1);
}
__global__ void kf_e2(Params p) {
    int gid = blockIdx.x * blockDim.x + threadIdx.x;
    int gsz = gridDim.x * blockDim.x;
    phase_e2(gid, gsz, p.src, p.dst, p.E, p.bmF1, p.bmNd, p.ctrl, p.e2s, p.e2d);
}
__global__ void kf_deg(Params p) {
    int gid = blockIdx.x * blockDim.x + threadIdx.x;
    int gsz = gridDim.x * blockDim.x;
    phase_deg(gid, gsz, p.dst, p.E, p.bmNd, p.deg);
}
__global__ void kf_h1(Params p) {
    __shared__ float a[NWAVE][CH];
    phase_h1(blockIdx.x, gridDim.x, threadIdx.x, p.x, p.W1, p.b1, p.deg, p.F1,
             p.ctrl, p.e2s, p.e2d, p.h1, a);
}
__global__ void kf_tail(Params p) {
    __shared__ float a2[2][CH];
    __shared__ float partial[2];
    phase_tail(threadIdx.x, p.h1, p.deg, p.pos1, p.np_, p.ctrl, p.e1s, p.e1d,
               p.W2, p.b2, p.fcW, p.fcb, p.out, a2, partial);
}

extern "C" void kernel_launch(void* const* d_in, const int* in_sizes, int n_in,
                              void* d_out, int out_size, void* d_ws, size_t ws_size,
                              hipStream_t stream) {
    const float* x   = (const float*)d_in[0];
    const int*   ei  = (const int*)d_in[1];
    const int*   np_ = (const int*)d_in[2];

    const int N = in_sizes[0] / CH;
    const int E = in_sizes[1] / 2;
    const int bmN = (N + 31) / 32;

    char* w = (char*)d_ws;
    size_t off = 0;
    auto alloc = [&](size_t bytes) {
        size_t o = off;
        off = (off + bytes + 255) & ~((size_t)255);
        return o;
    };
    // --- zeroed region (one small memset; also initializes barrier state) ---
    size_t o_bar  = alloc(256);                 // [0]=cnt, [32]=gen
    size_t o_ctrl = alloc(64);                  // [0]=cnt_e1 [1]=cnt_e2 [2]=nf1
    size_t o_bmF1 = alloc((size_t)bmN * 4);
    size_t o_bmNd = alloc((size_t)bmN * 4);
    size_t o_deg  = alloc((size_t)N * 4);
    size_t zero_end = off;
    // --- uninitialized region ---
    size_t o_pos  = alloc((size_t)N * 4);
    size_t o_e1s  = alloc((size_t)E1CAP * 4);
    size_t o_e1d  = alloc((size_t)E1CAP * 4);
    size_t o_F1   = alloc((size_t)F1CAP * 4);
    size_t o_e2s  = alloc((size_t)E2CAP * 4);
    size_t o_e2d  = alloc((size_t)E2CAP * 4);
    size_t o_h1   = alloc((size_t)F1CAP * CH * 4);
    (void)ws_size;

    Params p;
    p.x    = x;
    p.src  = ei;
    p.dst  = ei + E;
    p.np_  = np_;
    p.W1   = (const float*)d_in[3];
    p.b1   = (const float*)d_in[4];
    p.W2   = (const float*)d_in[5];
    p.b2   = (const float*)d_in[6];
    p.fcW  = (const float*)d_in[7];
    p.fcb  = (const float*)d_in[8];
    p.bar  = (int*)(w + o_bar);
    p.ctrl = (int*)(w + o_ctrl);
    p.bmF1 = (unsigned*)(w + o_bmF1);
    p.bmNd = (unsigned*)(w + o_bmNd);
    p.deg  = (int*)(w + o_deg);
    p.pos1 = (int*)(w + o_pos);
    p.e1s  = (int*)(w + o_e1s);
    p.e1d  = (int*)(w + o_e1d);
    p.F1   = (int*)(w + o_F1);
    p.e2s  = (int*)(w + o_e2s);
    p.e2d  = (int*)(w + o_e2d);
    p.h1   = (float*)(w + o_h1);
    p.out  = (float*)d_out;
    p.E = E; p.N = N; p.bmN = bmN; p.nblocks = GRID;

    (void)hipMemsetAsync(d_ws, 0, zero_end, stream);   // ~425 KB

    void* kargs[] = { &p };
    hipError_t err = hipLaunchCooperativeKernel((const void*)k_fused,
                                                dim3(GRID), dim3(BLK),
                                                kargs, 0, stream);
    if (err != hipSuccess) {
        // Fallback: multi-kernel path (no custom barriers needed)
        int scanBlocks = (E / 4 + 255) / 256;
        if (scanBlocks < 1) scanBlocks = 1;
        if (scanBlocks > 8192) scanBlocks = 8192;
        kf_e1f1<<<scanBlocks, 256, 0, stream>>>(p);
        kf_e2<<<scanBlocks, 256, 0, stream>>>(p);
        kf_deg<<<scanBlocks, 256, 0, stream>>>(p);
        kf_h1<<<160, 256, 0, stream>>>(p);
        kf_tail<<<1, 256, 0, stream>>>(p);
    }
}

// Round 5
// 154.709 us; speedup vs baseline: 3.5237x; 1.6911x over previous
//
#include <hip/hip_runtime.h>
#include <math.h>

// GCN link predictor, sparse-cone evaluation (round 7).
// Round-6 post-mortem: container died twice (no pytest output) -> likely GPU
// hang; round-6 was the first version able to hang (plain launch + unbounded
// grid-barrier spins). This round keeps the round-6 theory (flag-array
// barrier: no serialized same-address RMWs; plain launch: no ~110us coop
// overhead) and removes the hang surface:
//  - every spin loop is BOUNDED (~4M iters): a pathological barrier now
//    yields a wrong answer + counters instead of a dead container
//  - 64 blocks x 512 threads (one flag per poll lane; 512 waves << capacity)
//
// Phases (one plain launch, 5 flag barriers):
//  P1  scan dst: e1 edges (dst in {p0,p1}); register F1; zero agg1e   -- B1 --
//  P2  scan dst: e2 edges (dst in F1); need-bits src(e2)              -- B2 --
//  P3  scan dst: deg[d]++ if need-bit[d]                              -- B3 --
//  P4  edge-parallel: agg1e[pos1[u]][c] += dinv(s)dinv(u) x[s][c]     -- B4 --
//  P5  per-F1-row GEMM: h1 = relu((agg1e + dinv^2 x) @ W1 + b1)       -- B5 --
//  P6  block 0: layer-2 agg over e1 + @W2+b2, relu, fc, sigmoid

#define CH 64
#define E1CAP 4096
#define F1CAP (E1CAP + 2)
#define E2CAP 131072
#define GRID 64
#define BLK 512
#define NWAVE (BLK / 64)
#define GENIDX 1024
#define SPIN_MAX (1 << 22)

struct Params {
    const float* x;
    const int* src; const int* dst; const int* np_;
    const float* W1; const float* b1;
    const float* W2; const float* b2;
    const float* fcW; const float* fcb;
    int* bar;          // [16*b]=block b arrival gen (b<64), [1024]=published gen
    int* ctrl;         // [0]=cnt_e1 [1]=cnt_e2 [2]=nf1
    int* deg;
    unsigned* bmF1; unsigned* bmNd;
    int* pos1; int* e1s; int* e1d; int* F1;
    int* e2s; int* e2d; float* h1; float* agg1e;
    float* out;
    int E; int N; int bmN;
};

__device__ __forceinline__ float dinv_of(int degv) {
    return rsqrtf((float)(degv + 1));
}

__device__ __forceinline__ void st_agent(int* p, int v) {
    __hip_atomic_store(p, v, __ATOMIC_RELAXED, __HIP_MEMORY_SCOPE_AGENT);
}
__device__ __forceinline__ void st_agent_f(float* p, float v) {
    __hip_atomic_store(p, v, __ATOMIC_RELAXED, __HIP_MEMORY_SCOPE_AGENT);
}
__device__ __forceinline__ int ld_agent(const int* p) {
    return __hip_atomic_load((int*)p, __ATOMIC_RELAXED, __HIP_MEMORY_SCOPE_AGENT);
}

// Flag-array grid barrier (monotone generation per launch; GRID==64).
// Arrival: release-fence + per-block flag store (parallel, no RMW chain).
// Block 0 wave 0: each lane polls one flag; lane 0 publishes generation.
// Exit: bounded spin on generation + acquire-fence, then __syncthreads.
// All spins bounded: a broken invariant degrades to a wrong answer (bench
// fails with diagnostics) instead of a GPU hang.
__device__ __forceinline__ void gbar(int* bar, int phase) {
    __syncthreads();
    if (threadIdx.x == 0) {
        __builtin_amdgcn_fence(__ATOMIC_RELEASE, "agent");
        st_agent(&bar[blockIdx.x << 4], phase);
    }
    if (blockIdx.x == 0 && threadIdx.x < 64) {
        const int l = threadIdx.x;
        for (int it = 0; ; ++it) {
            int a = ld_agent(&bar[l << 4]);
            if (__all(a >= phase) || it > SPIN_MAX) break;
            __builtin_amdgcn_s_sleep(2);
        }
        if (l == 0) st_agent(&bar[GENIDX], phase);
    }
    if (threadIdx.x == 0) {
        int it = 0;
        while (ld_agent(&bar[GENIDX]) < phase && it++ < SPIN_MAX)
            __builtin_amdgcn_s_sleep(2);
        __builtin_amdgcn_fence(__ATOMIC_ACQUIRE, "agent");
    }
    __syncthreads();
}

__device__ __forceinline__ void reg_node(int u, unsigned* bmF1, unsigned* bmNd,
                                         int* ctrl, int* F1, int* pos1) {
    unsigned bit = 1u << (u & 31);
    unsigned old = atomicOr(&bmF1[u >> 5], bit);
    if (!(old & bit)) {
        atomicOr(&bmNd[u >> 5], bit);
        int i = atomicAdd(&ctrl[2], 1);
        st_agent(&F1[i], u);
        st_agent(&pos1[u], i);
    }
}

// P1: e1 collection + F1 registration + agg1e zeroing (agent stores).
__device__ __forceinline__ void phase_e1f1(int gid, int gsz,
                                           const int* __restrict__ src,
                                           const int* __restrict__ dst, int E,
                                           int p0, int p1, int* ctrl,
                                           int* e1s, int* e1d,
                                           unsigned* bmF1, unsigned* bmNd,
                                           int* F1, int* pos1,
                                           float* agg1e) {
    if (gid == 0) {
        reg_node(p0, bmF1, bmNd, ctrl, F1, pos1);
        if (p1 != p0) reg_node(p1, bmF1, bmNd, ctrl, F1, pos1);
    }
    for (int i = gid; i < F1CAP * CH; i += gsz) st_agent_f(&agg1e[i], 0.f);
    const int nvec = E >> 2;
    const int4* dst4 = (const int4*)dst;
    for (int i = gid; i < nvec; i += gsz) {
        int4 d4 = dst4[i];
        int ds[4] = {d4.x, d4.y, d4.z, d4.w};
#pragma unroll
        for (int k = 0; k < 4; k++) {
            int d = ds[k];
            if (d == p0 || d == p1) {
                int s = src[i * 4 + k];
                int idx = atomicAdd(&ctrl[0], 1);
                if (idx < E1CAP) { st_agent(&e1s[idx], s); st_agent(&e1d[idx], d); }
                reg_node(s, bmF1, bmNd, ctrl, F1, pos1);
            }
        }
    }
    for (int e = (nvec << 2) + gid; e < E; e += gsz) {
        int d = dst[e];
        if (d == p0 || d == p1) {
            int s = src[e];
            int idx = atomicAdd(&ctrl[0], 1);
            if (idx < E1CAP) { st_agent(&e1s[idx], s); st_agent(&e1d[idx], d); }
            reg_node(s, bmF1, bmNd, ctrl, F1, pos1);
        }
    }
}

__device__ __forceinline__ void phase_e2(int gid, int gsz,
                                         const int* __restrict__ src,
                                         const int* __restrict__ dst, int E,
                                         const unsigned* __restrict__ bmF1,
                                         unsigned* bmNd, int* ctrl,
                                         int* e2s, int* e2d) {
    const int nvec = E >> 2;
    const int4* dst4 = (const int4*)dst;
    for (int i = gid; i < nvec; i += gsz) {
        int4 d4 = dst4[i];
        int ds[4] = {d4.x, d4.y, d4.z, d4.w};
#pragma unroll
        for (int k = 0; k < 4; k++) {
            int d = ds[k];
            if ((bmF1[d >> 5] >> (d & 31)) & 1u) {
                int s = src[i * 4 + k];
                atomicOr(&bmNd[s >> 5], 1u << (s & 31));
                int idx = atomicAdd(&ctrl[1], 1);
                if (idx < E2CAP) { st_agent(&e2s[idx], s); st_agent(&e2d[idx], d); }
            }
        }
    }
    for (int e = (nvec << 2) + gid; e < E; e += gsz) {
        int d = dst[e];
        if ((bmF1[d >> 5] >> (d & 31)) & 1u) {
            int s = src[e];
            atomicOr(&bmNd[s >> 5], 1u << (s & 31));
            int idx = atomicAdd(&ctrl[1], 1);
            if (idx < E2CAP) { st_agent(&e2s[idx], s); st_agent(&e2d[idx], d); }
        }
    }
}

__device__ __forceinline__ void phase_deg(int gid, int gsz,
                                          const int* __restrict__ dst, int E,
                                          const unsigned* __restrict__ bmNd,
                                          int* deg) {
    const int nvec = E >> 2;
    const int4* dst4 = (const int4*)dst;
    for (int i = gid; i < nvec; i += gsz) {
        int4 d4 = dst4[i];
        int ds[4] = {d4.x, d4.y, d4.z, d4.w};
#pragma unroll
        for (int k = 0; k < 4; k++) {
            int d = ds[k];
            if ((bmNd[d >> 5] >> (d & 31)) & 1u) atomicAdd(&deg[d], 1);
        }
    }
    for (int e = (nvec << 2) + gid; e < E; e += gsz) {
        int d = dst[e];
        if ((bmNd[d >> 5] >> (d & 31)) & 1u) atomicAdd(&deg[d], 1);
    }
}

// P4: edge-parallel aggregation; 64 channels/edge, fire-and-forget atomics.
__device__ __forceinline__ void phase_agg(int gid, int gsz,
                                          const float* __restrict__ x,
                                          const int* __restrict__ deg,
                                          const int* __restrict__ pos1,
                                          const int* __restrict__ ctrl,
                                          const int* __restrict__ e2s,
                                          const int* __restrict__ e2d,
                                          float* __restrict__ agg1e) {
    int cnt2 = min(ctrl[1], E2CAP);
    int total = cnt2 << 6;
    for (int idx = gid; idx < total; idx += gsz) {
        int e = idx >> 6, c = idx & 63;
        int s = e2s[e], u = e2d[e];
        float nrm = dinv_of(deg[s]) * dinv_of(deg[u]);
        atomicAdd(&agg1e[pos1[u] * CH + c], nrm * x[(size_t)s * CH + c]);
    }
}

// P5: one F1 row per wave; GEMM row @ W1 + b1, relu.
__device__ __forceinline__ void phase_h1g(int blockId, int nBlocks, int tid,
                                          const float* __restrict__ x,
                                          const float* __restrict__ W1,
                                          const float* __restrict__ b1,
                                          const int* __restrict__ deg,
                                          const int* __restrict__ F1,
                                          const int* __restrict__ ctrl,
                                          const float* __restrict__ agg1e,
                                          float* __restrict__ h1,
                                          float (*a)[CH]) {
    int nf1 = min(ctrl[2], F1CAP);
    int w = tid >> 6, j = tid & 63;
    for (int i = blockId * NWAVE + w; i < nf1; i += nBlocks * NWAVE) {
        int u = F1[i];
        float du = dinv_of(deg[u]);
        a[w][j] = agg1e[i * CH + j] + du * du * x[(size_t)u * CH + j];
        // same-wave LDS RAW: no barrier needed
        float sum = b1[j];
#pragma unroll
        for (int k = 0; k < CH; k++) sum += a[w][k] * W1[k * CH + j];
        st_agent_f(&h1[i * CH + j], fmaxf(sum, 0.f));
    }
}

__device__ __forceinline__ void phase_tail(int tid,
                                           const float* __restrict__ h1,
                                           const int* __restrict__ deg,
                                           const int* __restrict__ pos1,
                                           const int* __restrict__ np_,
                                           const int* __restrict__ ctrl,
                                           const int* __restrict__ e1s,
                                           const int* __restrict__ e1d,
                                           const float* __restrict__ W2,
                                           const float* __restrict__ b2,
                                           const float* __restrict__ fcW,
                                           const float* __restrict__ fcb,
                                           float* __restrict__ out,
                                           float (*a2)[CH], float* partial) {
    int t = tid >> 6, j = tid & 63;
    if (tid < 128) {
        int pp = np_[t];
        float dp = dinv_of(deg[pp]);
        float acc = dp * dp * h1[pos1[pp] * CH + j];
        int cnt1 = min(ctrl[0], E1CAP);
        for (int e = 0; e < cnt1; e++) {
            int d = e1d[e];
            if (d == pp) {
                int s = e1s[e];
                acc += dinv_of(deg[s]) * dp * h1[pos1[s] * CH + j];
            }
        }
        a2[t][j] = acc;
    }
    __syncthreads();
    if (tid < 128) {
        float sum = b2[j];
#pragma unroll
        for (int k = 0; k < CH; k++) sum += a2[t][k] * W2[k * CH + j];
        float v = fmaxf(sum, 0.f);
        float pr = v * fcW[t * CH + j];
        for (int off = 32; off > 0; off >>= 1) pr += __shfl_down(pr, off);
        if (j == 0) partial[t] = pr;
    }
    __syncthreads();
    if (tid == 0) {
        float z = partial[0] + partial[1] + fcb[0];
        out[0] = 1.f / (1.f + expf(-z));
    }
}

__global__ __launch_bounds__(BLK, 1) void k_fused(Params p) {
    __shared__ float a[NWAVE][CH];
    __shared__ float a2[2][CH];
    __shared__ float partial[2];
    const int gid = blockIdx.x * BLK + threadIdx.x;
    const int gsz = GRID * BLK;

    phase_e1f1(gid, gsz, p.src, p.dst, p.E, p.np_[0], p.np_[1], p.ctrl,
               p.e1s, p.e1d, p.bmF1, p.bmNd, p.F1, p.pos1, p.agg1e);
    gbar(p.bar, 1);
    phase_e2(gid, gsz, p.src, p.dst, p.E, p.bmF1, p.bmNd, p.ctrl, p.e2s, p.e2d);
    gbar(p.bar, 2);
    phase_deg(gid, gsz, p.dst, p.E, p.bmNd, p.deg);
    gbar(p.bar, 3);
    phase_agg(gid, gsz, p.x, p.deg, p.pos1, p.ctrl, p.e2s, p.e2d, p.agg1e);
    gbar(p.bar, 4);
    phase_h1g(blockIdx.x, GRID, threadIdx.x, p.x, p.W1, p.b1, p.deg, p.F1,
              p.ctrl, p.agg1e, p.h1, a);
    gbar(p.bar, 5);
    if (blockIdx.x == 0)
        phase_tail(threadIdx.x, p.h1, p.deg, p.pos1, p.np_, p.ctrl, p.e1s, p.e1d,
                   p.W2, p.b2, p.fcW, p.fcb, p.out, a2, partial);
}

extern "C" void kernel_launch(void* const* d_in, const int* in_sizes, int n_in,
                              void* d_out, int out_size, void* d_ws, size_t ws_size,
                              hipStream_t stream) {
    const float* x   = (const float*)d_in[0];
    const int*   ei  = (const int*)d_in[1];
    const int*   np_ = (const int*)d_in[2];

    const int N = in_sizes[0] / CH;
    const int E = in_sizes[1] / 2;
    const int bmN = (N + 31) / 32;

    char* w = (char*)d_ws;
    size_t off = 0;
    auto alloc = [&](size_t bytes) {
        size_t o = off;
        off = (off + bytes + 255) & ~((size_t)255);
        return o;
    };
    // --- zeroed region (one small memset; initializes barrier state) ---
    size_t o_bar  = alloc(8192);                // flags[64*16] + gen[1024]
    size_t o_ctrl = alloc(64);                  // [0]=cnt_e1 [1]=cnt_e2 [2]=nf1
    size_t o_bmF1 = alloc((size_t)bmN * 4);
    size_t o_bmNd = alloc((size_t)bmN * 4);
    size_t o_deg  = alloc((size_t)N * 4);
    size_t zero_end = off;
    // --- uninitialized region (agg1e zeroed in-kernel via agent stores) ---
    size_t o_pos  = alloc((size_t)N * 4);
    size_t o_e1s  = alloc((size_t)E1CAP * 4);
    size_t o_e1d  = alloc((size_t)E1CAP * 4);
    size_t o_F1   = alloc((size_t)F1CAP * 4);
    size_t o_e2s  = alloc((size_t)E2CAP * 4);
    size_t o_e2d  = alloc((size_t)E2CAP * 4);
    size_t o_h1   = alloc((size_t)F1CAP * CH * 4);
    size_t o_agg  = alloc((size_t)F1CAP * CH * 4);
    (void)ws_size;

    Params p;
    p.x    = x;
    p.src  = ei;
    p.dst  = ei + E;
    p.np_  = np_;
    p.W1   = (const float*)d_in[3];
    p.b1   = (const float*)d_in[4];
    p.W2   = (const float*)d_in[5];
    p.b2   = (const float*)d_in[6];
    p.fcW  = (const float*)d_in[7];
    p.fcb  = (const float*)d_in[8];
    p.bar   = (int*)(w + o_bar);
    p.ctrl  = (int*)(w + o_ctrl);
    p.bmF1  = (unsigned*)(w + o_bmF1);
    p.bmNd  = (unsigned*)(w + o_bmNd);
    p.deg   = (int*)(w + o_deg);
    p.pos1  = (int*)(w + o_pos);
    p.e1s   = (int*)(w + o_e1s);
    p.e1d   = (int*)(w + o_e1d);
    p.F1    = (int*)(w + o_F1);
    p.e2s   = (int*)(w + o_e2s);
    p.e2d   = (int*)(w + o_e2d);
    p.h1    = (float*)(w + o_h1);
    p.agg1e = (float*)(w + o_agg);
    p.out  = (float*)d_out;
    p.E = E; p.N = N; p.bmN = bmN;

    (void)hipMemsetAsync(d_ws, 0, zero_end, stream);   // ~434 KB

    k_fused<<<GRID, BLK, 0, stream>>>(p);
}

// Round 6
// 136.819 us; speedup vs baseline: 3.9844x; 1.1308x over previous
//
#include <hip/hip_runtime.h>
#include <math.h>

// GCN link predictor, sparse-cone evaluation (round 8).
// Round-7 post-mortem: flag barrier + plain launch => kernel 150 -> 77 us
// (pass). Residual decomposition: two-stage barrier (arrive -> block0 poll ->
// publish -> observe = 2 LLC round trips) x5; scans on only 64 blocks with
// post-fence cold caches; +1MB in-kernel agg1e zeroing (WRITE 0.4->1.58MB).
// This round:
//  - single-stage barrier: every block's wave-0 polls all 128 flags directly
//    (one LLC round trip; no publish step)
//  - 128 blocks x 512 threads: halves exposed scan latency
//  - agg1e zeroing moved back to the hipMemsetAsync (fill engine)
//  - tail aggregation 8-way wave-parallel (was 2 serial ~16-edge chains)
//
// Phases (one plain launch, 5 flag barriers):
//  P1  scan dst: e1 edges (dst in {p0,p1}); register F1           -- B1 --
//  P2  scan dst: e2 edges (dst in F1); need-bits src(e2)          -- B2 --
//  P3  scan dst: deg[d]++ if need-bit[d]                          -- B3 --
//  P4  edge-parallel: agg1e[pos1[u]][c] += dinv(s)dinv(u) x[s][c] -- B4 --
//  P5  per-F1-row GEMM: h1 = relu((agg1e + dinv^2 x) @ W1 + b1)   -- B5 --
//  P6  block 0: layer-2 agg over e1 (8-wave) + @W2+b2, relu, fc, sigmoid

#define CH 64
#define E1CAP 4096
#define F1CAP (E1CAP + 2)
#define E2CAP 131072
#define GRID 128
#define BLK 512
#define NWAVE (BLK / 64)
#define SPIN_MAX (1 << 20)

struct Params {
    const float* x;
    const int* src; const int* dst; const int* np_;
    const float* W1; const float* b1;
    const float* W2; const float* b2;
    const float* fcW; const float* fcb;
    int* bar;          // [16*b] = block b arrival generation (64B stride)
    int* ctrl;         // [0]=cnt_e1 [1]=cnt_e2 [2]=nf1
    int* deg;
    unsigned* bmF1; unsigned* bmNd;
    int* pos1; int* e1s; int* e1d; int* F1;
    int* e2s; int* e2d; float* h1; float* agg1e;
    float* out;
    int E; int N; int bmN;
};

__device__ __forceinline__ float dinv_of(int degv) {
    return rsqrtf((float)(degv + 1));
}

__device__ __forceinline__ void st_agent(int* p, int v) {
    __hip_atomic_store(p, v, __ATOMIC_RELAXED, __HIP_MEMORY_SCOPE_AGENT);
}
__device__ __forceinline__ void st_agent_f(float* p, float v) {
    __hip_atomic_store(p, v, __ATOMIC_RELAXED, __HIP_MEMORY_SCOPE_AGENT);
}
__device__ __forceinline__ int ld_agent(const int* p) {
    return __hip_atomic_load((int*)p, __ATOMIC_RELAXED, __HIP_MEMORY_SCOPE_AGENT);
}

// Single-stage flag-array grid barrier (monotone generation; GRID==128).
// Arrival: release-fence (publish this block's writes) + per-block flag store.
// Completion: every block's wave 0 polls all 128 flags (2/lane, agent loads);
// one LLC round trip after the last arrival. Exit: acquire-fence.
// All spins bounded: pathology degrades to wrong answer, not a GPU hang.
__device__ __forceinline__ void gbar(int* bar, int phase) {
    __syncthreads();
    if (threadIdx.x == 0) {
        __builtin_amdgcn_fence(__ATOMIC_RELEASE, "agent");
        st_agent(&bar[blockIdx.x << 4], phase);
    }
    if (threadIdx.x < 64) {
        const int l = threadIdx.x;
        for (int it = 0; ; ++it) {
            int a = ld_agent(&bar[l << 4]);
            int b = ld_agent(&bar[(l + 64) << 4]);
            if (__all(a >= phase && b >= phase) || it > SPIN_MAX) break;
            __builtin_amdgcn_s_sleep(1);
        }
    }
    if (threadIdx.x == 0)
        __builtin_amdgcn_fence(__ATOMIC_ACQUIRE, "agent");
    __syncthreads();
}

__device__ __forceinline__ void reg_node(int u, unsigned* bmF1, unsigned* bmNd,
                                         int* ctrl, int* F1, int* pos1) {
    unsigned bit = 1u << (u & 31);
    unsigned old = atomicOr(&bmF1[u >> 5], bit);
    if (!(old & bit)) {
        atomicOr(&bmNd[u >> 5], bit);
        int i = atomicAdd(&ctrl[2], 1);
        st_agent(&F1[i], u);
        st_agent(&pos1[u], i);
    }
}

// P1: e1 collection + F1 registration.
__device__ __forceinline__ void phase_e1f1(int gid, int gsz,
                                           const int* __restrict__ src,
                                           const int* __restrict__ dst, int E,
                                           int p0, int p1, int* ctrl,
                                           int* e1s, int* e1d,
                                           unsigned* bmF1, unsigned* bmNd,
                                           int* F1, int* pos1) {
    if (gid == 0) {
        reg_node(p0, bmF1, bmNd, ctrl, F1, pos1);
        if (p1 != p0) reg_node(p1, bmF1, bmNd, ctrl, F1, pos1);
    }
    const int nvec = E >> 2;
    const int4* dst4 = (const int4*)dst;
    for (int i = gid; i < nvec; i += gsz) {
        int4 d4 = dst4[i];
        int ds[4] = {d4.x, d4.y, d4.z, d4.w};
#pragma unroll
        for (int k = 0; k < 4; k++) {
            int d = ds[k];
            if (d == p0 || d == p1) {
                int s = src[i * 4 + k];
                int idx = atomicAdd(&ctrl[0], 1);
                if (idx < E1CAP) { st_agent(&e1s[idx], s); st_agent(&e1d[idx], d); }
                reg_node(s, bmF1, bmNd, ctrl, F1, pos1);
            }
        }
    }
    for (int e = (nvec << 2) + gid; e < E; e += gsz) {
        int d = dst[e];
        if (d == p0 || d == p1) {
            int s = src[e];
            int idx = atomicAdd(&ctrl[0], 1);
            if (idx < E1CAP) { st_agent(&e1s[idx], s); st_agent(&e1d[idx], d); }
            reg_node(s, bmF1, bmNd, ctrl, F1, pos1);
        }
    }
}

__device__ __forceinline__ void phase_e2(int gid, int gsz,
                                         const int* __restrict__ src,
                                         const int* __restrict__ dst, int E,
                                         const unsigned* __restrict__ bmF1,
                                         unsigned* bmNd, int* ctrl,
                                         int* e2s, int* e2d) {
    const int nvec = E >> 2;
    const int4* dst4 = (const int4*)dst;
    for (int i = gid; i < nvec; i += gsz) {
        int4 d4 = dst4[i];
        int ds[4] = {d4.x, d4.y, d4.z, d4.w};
#pragma unroll
        for (int k = 0; k < 4; k++) {
            int d = ds[k];
            if ((bmF1[d >> 5] >> (d & 31)) & 1u) {
                int s = src[i * 4 + k];
                atomicOr(&bmNd[s >> 5], 1u << (s & 31));
                int idx = atomicAdd(&ctrl[1], 1);
                if (idx < E2CAP) { st_agent(&e2s[idx], s); st_agent(&e2d[idx], d); }
            }
        }
    }
    for (int e = (nvec << 2) + gid; e < E; e += gsz) {
        int d = dst[e];
        if ((bmF1[d >> 5] >> (d & 31)) & 1u) {
            int s = src[e];
            atomicOr(&bmNd[s >> 5], 1u << (s & 31));
            int idx = atomicAdd(&ctrl[1], 1);
            if (idx < E2CAP) { st_agent(&e2s[idx], s); st_agent(&e2d[idx], d); }
        }
    }
}

__device__ __forceinline__ void phase_deg(int gid, int gsz,
                                          const int* __restrict__ dst, int E,
                                          const unsigned* __restrict__ bmNd,
                                          int* deg) {
    const int nvec = E >> 2;
    const int4* dst4 = (const int4*)dst;
    for (int i = gid; i < nvec; i += gsz) {
        int4 d4 = dst4[i];
        int ds[4] = {d4.x, d4.y, d4.z, d4.w};
#pragma unroll
        for (int k = 0; k < 4; k++) {
            int d = ds[k];
            if ((bmNd[d >> 5] >> (d & 31)) & 1u) atomicAdd(&deg[d], 1);
        }
    }
    for (int e = (nvec << 2) + gid; e < E; e += gsz) {
        int d = dst[e];
        if ((bmNd[d >> 5] >> (d & 31)) & 1u) atomicAdd(&deg[d], 1);
    }
}

// P4: edge-parallel aggregation; 64 channels/edge, fire-and-forget atomics.
__device__ __forceinline__ void phase_agg(int gid, int gsz,
                                          const float* __restrict__ x,
                                          const int* __restrict__ deg,
                                          const int* __restrict__ pos1,
                                          const int* __restrict__ ctrl,
                                          const int* __restrict__ e2s,
                                          const int* __restrict__ e2d,
                                          float* __restrict__ agg1e) {
    int cnt2 = min(ctrl[1], E2CAP);
    int total = cnt2 << 6;
    for (int idx = gid; idx < total; idx += gsz) {
        int e = idx >> 6, c = idx & 63;
        int s = e2s[e], u = e2d[e];
        float nrm = dinv_of(deg[s]) * dinv_of(deg[u]);
        atomicAdd(&agg1e[pos1[u] * CH + c], nrm * x[(size_t)s * CH + c]);
    }
}

// P5: one F1 row per wave; GEMM row @ W1 + b1, relu.
__device__ __forceinline__ void phase_h1g(int blockId, int nBlocks, int tid,
                                          const float* __restrict__ x,
                                          const float* __restrict__ W1,
                                          const float* __restrict__ b1,
                                          const int* __restrict__ deg,
                                          const int* __restrict__ F1,
                                          const int* __restrict__ ctrl,
                                          const float* __restrict__ agg1e,
                                          float* __restrict__ h1,
                                          float (*a)[CH]) {
    int nf1 = min(ctrl[2], F1CAP);
    int w = tid >> 6, j = tid & 63;
    for (int i = blockId * NWAVE + w; i < nf1; i += nBlocks * NWAVE) {
        int u = F1[i];
        float du = dinv_of(deg[u]);
        a[w][j] = agg1e[i * CH + j] + du * du * x[(size_t)u * CH + j];
        // same-wave LDS RAW: no barrier needed
        float sum = b1[j];
#pragma unroll
        for (int k = 0; k < CH; k++) sum += a[w][k] * W1[k * CH + j];
        st_agent_f(&h1[i * CH + j], fmaxf(sum, 0.f));
    }
}

// P6 (block 0): 8-wave layer-2 aggregation (4 waves per endpoint, stride-4
// over e1, LDS partial reduce) + @W2+b2, relu, fc, sigmoid.
__device__ __forceinline__ void phase_tail(int tid,
                                           const float* __restrict__ h1,
                                           const int* __restrict__ deg,
                                           const int* __restrict__ pos1,
                                           const int* __restrict__ np_,
                                           const int* __restrict__ ctrl,
                                           const int* __restrict__ e1s,
                                           const int* __restrict__ e1d,
                                           const float* __restrict__ W2,
                                           const float* __restrict__ b2,
                                           const float* __restrict__ fcW,
                                           const float* __restrict__ fcb,
                                           float* __restrict__ out,
                                           float (*a2p)[CH], float (*a2)[CH],
                                           float* partial) {
    int w = tid >> 6, j = tid & 63;
    int t = w >> 2, sub = w & 3;          // 4 waves per endpoint
    int pp = np_[t];
    float dp = dinv_of(deg[pp]);
    float acc = (sub == 0) ? dp * dp * h1[pos1[pp] * CH + j] : 0.f;
    int cnt1 = min(ctrl[0], E1CAP);
    for (int e = sub; e < cnt1; e += 4) {
        if (e1d[e] == pp) {
            int s = e1s[e];
            acc += dinv_of(deg[s]) * dp * h1[pos1[s] * CH + j];
        }
    }
    a2p[w][j] = acc;
    __syncthreads();
    if (tid < 128) {
        int t2 = tid >> 6;
        a2[t2][j] = a2p[t2 * 4][j] + a2p[t2 * 4 + 1][j] +
                    a2p[t2 * 4 + 2][j] + a2p[t2 * 4 + 3][j];
    }
    __syncthreads();
    if (tid < 128) {
        int t2 = tid >> 6;
        float sum = b2[j];
#pragma unroll
        for (int k = 0; k < CH; k++) sum += a2[t2][k] * W2[k * CH + j];
        float v = fmaxf(sum, 0.f);
        float pr = v * fcW[t2 * CH + j];
        for (int off = 32; off > 0; off >>= 1) pr += __shfl_down(pr, off);
        if (j == 0) partial[t2] = pr;
    }
    __syncthreads();
    if (tid == 0) {
        float z = partial[0] + partial[1] + fcb[0];
        out[0] = 1.f / (1.f + expf(-z));
    }
}

__global__ __launch_bounds__(BLK, 1) void k_fused(Params p) {
    __shared__ float a[NWAVE][CH];
    __shared__ float a2p[NWAVE][CH];
    __shared__ float a2[2][CH];
    __shared__ float partial[2];
    const int gid = blockIdx.x * BLK + threadIdx.x;
    const int gsz = GRID * BLK;

    phase_e1f1(gid, gsz, p.src, p.dst, p.E, p.np_[0], p.np_[1], p.ctrl,
               p.e1s, p.e1d, p.bmF1, p.bmNd, p.F1, p.pos1);
    gbar(p.bar, 1);
    phase_e2(gid, gsz, p.src, p.dst, p.E, p.bmF1, p.bmNd, p.ctrl, p.e2s, p.e2d);
    gbar(p.bar, 2);
    phase_deg(gid, gsz, p.dst, p.E, p.bmNd, p.deg);
    gbar(p.bar, 3);
    phase_agg(gid, gsz, p.x, p.deg, p.pos1, p.ctrl, p.e2s, p.e2d, p.agg1e);
    gbar(p.bar, 4);
    phase_h1g(blockIdx.x, GRID, threadIdx.x, p.x, p.W1, p.b1, p.deg, p.F1,
              p.ctrl, p.agg1e, p.h1, a);
    gbar(p.bar, 5);
    if (blockIdx.x == 0)
        phase_tail(threadIdx.x, p.h1, p.deg, p.pos1, p.np_, p.ctrl, p.e1s, p.e1d,
                   p.W2, p.b2, p.fcW, p.fcb, p.out, a2p, a2, partial);
}

extern "C" void kernel_launch(void* const* d_in, const int* in_sizes, int n_in,
                              void* d_out, int out_size, void* d_ws, size_t ws_size,
                              hipStream_t stream) {
    const float* x   = (const float*)d_in[0];
    const int*   ei  = (const int*)d_in[1];
    const int*   np_ = (const int*)d_in[2];

    const int N = in_sizes[0] / CH;
    const int E = in_sizes[1] / 2;
    const int bmN = (N + 31) / 32;

    char* w = (char*)d_ws;
    size_t off = 0;
    auto alloc = [&](size_t bytes) {
        size_t o = off;
        off = (off + bytes + 255) & ~((size_t)255);
        return o;
    };
    // --- zeroed region (one memset; barrier flags + ctrl + bitmaps + deg
    //     + agg1e; ~1.5 MB at fill-engine rate) ---
    size_t o_bar  = alloc((size_t)GRID * 16 * 4);   // 64B-strided flags
    size_t o_ctrl = alloc(64);                      // cnt_e1, cnt_e2, nf1
    size_t o_bmF1 = alloc((size_t)bmN * 4);
    size_t o_bmNd = alloc((size_t)bmN * 4);
    size_t o_deg  = alloc((size_t)N * 4);
    size_t o_agg  = alloc((size_t)F1CAP * CH * 4);
    size_t zero_end = off;
    // --- uninitialized region ---
    size_t o_pos  = alloc((size_t)N * 4);
    size_t o_e1s  = alloc((size_t)E1CAP * 4);
    size_t o_e1d  = alloc((size_t)E1CAP * 4);
    size_t o_F1   = alloc((size_t)F1CAP * 4);
    size_t o_e2s  = alloc((size_t)E2CAP * 4);
    size_t o_e2d  = alloc((size_t)E2CAP * 4);
    size_t o_h1   = alloc((size_t)F1CAP * CH * 4);
    (void)ws_size;

    Params p;
    p.x    = x;
    p.src  = ei;
    p.dst  = ei + E;
    p.np_  = np_;
    p.W1   = (const float*)d_in[3];
    p.b1   = (const float*)d_in[4];
    p.W2   = (const float*)d_in[5];
    p.b2   = (const float*)d_in[6];
    p.fcW  = (const float*)d_in[7];
    p.fcb  = (const float*)d_in[8];
    p.bar   = (int*)(w + o_bar);
    p.ctrl  = (int*)(w + o_ctrl);
    p.bmF1  = (unsigned*)(w + o_bmF1);
    p.bmNd  = (unsigned*)(w + o_bmNd);
    p.deg   = (int*)(w + o_deg);
    p.agg1e = (float*)(w + o_agg);
    p.pos1  = (int*)(w + o_pos);
    p.e1s   = (int*)(w + o_e1s);
    p.e1d   = (int*)(w + o_e1d);
    p.F1    = (int*)(w + o_F1);
    p.e2s   = (int*)(w + o_e2s);
    p.e2d   = (int*)(w + o_e2d);
    p.h1    = (float*)(w + o_h1);
    p.out  = (float*)d_out;
    p.E = E; p.N = N; p.bmN = bmN;

    (void)hipMemsetAsync(d_ws, 0, zero_end, stream);   // ~1.5 MB

    k_fused<<<GRID, BLK, 0, stream>>>(p);
}